// Round 1
// 2141.276 us; speedup vs baseline: 1.0036x; 1.0036x over previous
//
#include <hip/hip_runtime.h>

// SDEBlock3D via implicit-GEMM MFMA (bf16), 20 Euler-Maruyama steps.
// This round: padded (66^3) zero-halo layouts for yb/h -> no bounds checks,
// NO LDS staging (B-fragments loaded directly from L1/L2, layouts match the
// MFMA B lane mapping), and z-rotation accumulators (each input plane feeds
// 3 output planes; 9 fragment loads per 27 MFMAs instead of 27).
//   y   fp32 [16][64^3] channel-major, master state in d_out.
//   ybp bf16 [66][66][66][16] channels-last padded (conv1 input), in d_ws.
//   hbp bf16 [66][66][66][64] channels-last padded (conv2 input), in d_ws.

#define S    64
#define SS   4096
#define SSS  262144
#define DT_F 0.05f
#define SIG_SDT 0.022360679774997897f  // 0.1*sqrt(0.05)
#define PD   66                        // padded side (halo of 1 each side)

typedef __bf16 bf16x8 __attribute__((ext_vector_type(8)));
typedef float  f32x4  __attribute__((ext_vector_type(4)));
typedef float  f32x16 __attribute__((ext_vector_type(16)));

union B8U { uint4 u; bf16x8 b; };
__device__ inline bf16x8 as_bf16x8(uint4 u) { B8U x; x.u = u; return x.b; }

__device__ inline unsigned short bf16_bits(float f) {
    union { float f; unsigned u; } c; c.f = f;
    unsigned r = c.u + 0x7fffu + ((c.u >> 16) & 1u);   // RNE
    return (unsigned short)(r >> 16);
}

__device__ inline float tanh_fast(float v) {
    float a = fminf(fmaxf(v, -15.f), 15.f);
    float e = __expf(2.f * a);
    return (e - 1.f) * __builtin_amdgcn_rcpf(e + 1.f);
}

// ---------------------------------------------------------------------------
// Zero the padded volumes once per launch (ws is re-poisoned by the harness).
// Interior is fully rewritten every step; pads stay zero forever.
// ---------------------------------------------------------------------------
__global__ void zero_ws(uint4* __restrict__ p, unsigned n)
{
    const uint4 z = {0u, 0u, 0u, 0u};
    for (unsigned i = blockIdx.x * 256u + threadIdx.x; i < n; i += gridDim.x * 256u)
        p[i] = z;
}

// ---------------------------------------------------------------------------
// Weight prep (unchanged, verified fragment orders):
// w1t: frag(tap, mtile): lane l elem j -> A[m=mt*32+(l&31)][k=(l>>5)*8+j]
// w2t: frag(tap, kc)   : lane l elem j -> A[m=l&15][k=(l>>4)*8+j], ic=kc*32+k
// ---------------------------------------------------------------------------
__global__ void prep_weights(const float* __restrict__ w1, const float* __restrict__ w2,
                             unsigned short* __restrict__ w1t, unsigned short* __restrict__ w2t)
{
    const int t = blockIdx.x * 256 + threadIdx.x;
    if (t >= 27 * 2 * 64 * 8) return;
    const int j = t & 7, l = (t >> 3) & 63, half = (t >> 9) & 1, tap = t >> 10;
    {
        const int oc = half * 32 + (l & 31), ic = (l >> 5) * 8 + j;
        w1t[t] = bf16_bits(w1[(oc * 16 + ic) * 27 + tap]);
    }
    {
        const int oc = l & 15, ic = half * 32 + (l >> 4) * 8 + j;
        w2t[t] = bf16_bits(w2[(oc * 64 + ic) * 27 + tap]);
    }
}

// x fp32 [16][S^3] -> ybp bf16 padded [z+1][y+1][x+1][16]
__global__ void pack_x(const float* __restrict__ x, char* __restrict__ ybp)
{
    const int p = blockIdx.x * 256 + threadIdx.x;
    const int z = p >> 12, yy = (p >> 6) & 63, xx = p & 63;
    union { unsigned short s[16]; uint4 v[2]; } pk;
    #pragma unroll
    for (int c = 0; c < 16; ++c) pk.s[c] = bf16_bits(x[c * SSS + p]);
    char* dst = ybp + (((size_t)(z + 1) * PD + (yy + 1)) * PD + (xx + 1)) * 32;
    *(uint4*)dst        = pk.v[0];
    *(uint4*)(dst + 16) = pk.v[1];
}

// ---------------------------------------------------------------------------
// conv1: ybp -> hbp, 32x32x16 MFMA, fused bias+tanh. NO LDS, no barriers.
// Block 256 = 4 waves: wave = (mt = w>>1 (oc half), xg = w&1 (px half)).
// Each wave: one y row, z-chunk of 8, 32 px x 32 oc per plane.
// z-rotation: input plane zp feeds outputs zp-1 (dz2), zp (dz1), zp+1 (dz0).
// B frag (lane l): px = x0 + dx + (l&31), ic chunk = (l>>5)*8 -> one uint4
// load directly from ybp (16B/lane, coalesced). Grid dim3(8, 64).
// ---------------------------------------------------------------------------
__global__ __launch_bounds__(256, 2)
void conv1_mfma(const char* __restrict__ ybp, const uint4* __restrict__ w1t,
                const float* __restrict__ b1, char* __restrict__ hbp)
{
    const int t = threadIdx.x, lane = t & 63, w = t >> 6;
    const int mt = w >> 1, xg = w & 1;
    const int y = blockIdx.y, z0 = blockIdx.x * 8;
    const int n = lane & 31, hh = lane >> 5;
    const int x0 = xg * 32;

    bf16x8 A[27];
    #pragma unroll
    for (int tap = 0; tap < 27; ++tap)
        A[tap] = as_bf16x8(w1t[(tap * 2 + mt) * 64 + lane]);

    float bias[16];
    #pragma unroll
    for (int q = 0; q < 4; ++q)
        #pragma unroll
        for (int j = 0; j < 4; ++j)
            bias[q * 4 + j] = b1[mt * 32 + q * 8 + hh * 4 + j];

    // per-lane bases (uniform offsets added per access)
    const char* ybl = ybp + (x0 + n) * 32 + hh * 16;
    char* hbl = hbp + ((size_t)(y + 1) * PD + (x0 + n + 1)) * 128
                    + (mt * 32 + hh * 4) * 2;

    f32x16 acc[3];
    #pragma unroll
    for (int s = 0; s < 3; ++s)
        #pragma unroll
        for (int q = 0; q < 16; ++q) acc[s][q] = 0.f;

    #pragma unroll
    for (int i = 0; i < 10; ++i) {
        const int zp = z0 - 1 + i;   // input plane (unpadded coords)
        const char* pb = ybl + ((size_t)(zp + 1) * PD + y) * (PD * 32);
        #pragma unroll
        for (int dy = 0; dy < 3; ++dy) {
            #pragma unroll
            for (int dx = 0; dx < 3; ++dx) {
                bf16x8 B = as_bf16x8(*(const uint4*)(pb + (dy * PD + dx) * 32));
                if (i < 8)                      // out z = zp+1, tap dz=0
                    acc[(i + 1) % 3] = __builtin_amdgcn_mfma_f32_32x32x16_bf16(
                        A[0 + dy * 3 + dx], B, acc[(i + 1) % 3], 0, 0, 0);
                if (i >= 1 && i <= 8)           // out z = zp,   tap dz=1
                    acc[i % 3] = __builtin_amdgcn_mfma_f32_32x32x16_bf16(
                        A[9 + dy * 3 + dx], B, acc[i % 3], 0, 0, 0);
                if (i >= 2)                     // out z = zp-1, tap dz=2
                    acc[(i + 2) % 3] = __builtin_amdgcn_mfma_f32_32x32x16_bf16(
                        A[18 + dy * 3 + dx], B, acc[(i + 2) % 3], 0, 0, 0);
            }
        }
        if (i >= 2) {                           // out plane zp-1 complete
            const int z = zp - 1;
            char* hp = hbl + (size_t)(z + 1) * (PD * PD * 128);
            f32x16 a = acc[(i + 2) % 3];
            // D layout 32x32: col = lane&31 (=px), row = (reg&3)+8*(reg>>2)+4*hh
            #pragma unroll
            for (int q = 0; q < 4; ++q) {
                union { unsigned short sh[4]; uint2 v; } pk;
                #pragma unroll
                for (int j = 0; j < 4; ++j)
                    pk.sh[j] = bf16_bits(tanh_fast(a[q * 4 + j] + bias[q * 4 + j]));
                *(uint2*)(hp + q * 16) = pk.v;
            }
            #pragma unroll
            for (int q = 0; q < 16; ++q) acc[(i + 2) % 3][q] = 0.f;
        }
    }
}

// ---------------------------------------------------------------------------
// conv2: hbp -> Euler update of y fp32 + ybp bf16, 16x16x32 MFMA.
// Block 128 = 2 waves: wave = kc (ic half). Each wave: 16 px x 16 oc per
// plane, one y row, z-chunk of 8, z-rotation accs (f32x4 x3).
// kc partials reduced via tiny LDS scratch (one barrier per output plane).
// B frag (lane l): px = x0 + dx + (l&15), ic = kc*32 + (l>>4)*8 -> one uint4
// load directly from hbp. Grid dim3(4, 64, 8).
// ---------------------------------------------------------------------------
__global__ __launch_bounds__(128, 3)
void conv2_mfma(const char* __restrict__ hbp, const uint4* __restrict__ w2t,
                const float* __restrict__ b2, const float* __restrict__ ysrc,
                float* __restrict__ ydst, char* __restrict__ ybp,
                const float* __restrict__ nz)
{
    __shared__ f32x4 scratch[2][64];
    const int t = threadIdx.x, lane = t & 63, kc = t >> 6;
    const int y = blockIdx.y, z0 = blockIdx.z * 8, x0 = blockIdx.x * 16;
    const int n16 = lane & 15, g = lane >> 4;

    bf16x8 A[27];
    #pragma unroll
    for (int tap = 0; tap < 27; ++tap)
        A[tap] = as_bf16x8(w2t[(tap * 2 + kc) * 64 + lane]);

    float b2v[4];
    #pragma unroll
    for (int j = 0; j < 4; ++j) b2v[j] = b2[g * 4 + j];

    const char* hbl = hbp + (x0 + n16) * 128 + kc * 64 + g * 16;

    f32x4 acc[3];
    #pragma unroll
    for (int s = 0; s < 3; ++s)
        #pragma unroll
        for (int q = 0; q < 4; ++q) acc[s][q] = 0.f;

    #pragma unroll
    for (int i = 0; i < 10; ++i) {
        const int zp = z0 - 1 + i;
        const char* pb = hbl + ((size_t)(zp + 1) * PD + y) * (PD * 128);
        #pragma unroll
        for (int dy = 0; dy < 3; ++dy) {
            #pragma unroll
            for (int dx = 0; dx < 3; ++dx) {
                bf16x8 B = as_bf16x8(*(const uint4*)(pb + (dy * PD + dx) * 128));
                if (i < 8)
                    acc[(i + 1) % 3] = __builtin_amdgcn_mfma_f32_16x16x32_bf16(
                        A[0 + dy * 3 + dx], B, acc[(i + 1) % 3], 0, 0, 0);
                if (i >= 1 && i <= 8)
                    acc[i % 3] = __builtin_amdgcn_mfma_f32_16x16x32_bf16(
                        A[9 + dy * 3 + dx], B, acc[i % 3], 0, 0, 0);
                if (i >= 2)
                    acc[(i + 2) % 3] = __builtin_amdgcn_mfma_f32_16x16x32_bf16(
                        A[18 + dy * 3 + dx], B, acc[(i + 2) % 3], 0, 0, 0);
            }
        }
        if (i >= 2) {
            const int z = zp - 1;
            f32x4 a = acc[(i + 2) % 3];
            #pragma unroll
            for (int q = 0; q < 4; ++q) acc[(i + 2) % 3][q] = 0.f;
            if (kc == 1) scratch[i & 1][lane] = a;
            __syncthreads();
            if (kc == 0) {
                f32x4 o = scratch[i & 1][lane];
                // D layout 16x16: col = lane&15 (=px), row = g*4 + reg (=oc)
                const size_t p = (size_t)z * SS + y * S + (x0 + n16);
                union { unsigned short sh[4]; uint2 v; } pk;
                #pragma unroll
                for (int j = 0; j < 4; ++j) {
                    const size_t idx = (size_t)(g * 4 + j) * SSS + p;
                    const float f  = a[j] + o[j] + b2v[j];
                    const float yv = ysrc[idx] + f * DT_F + SIG_SDT * nz[idx];
                    ydst[idx] = yv;
                    pk.sh[j] = bf16_bits(yv);
                }
                char* yb = ybp + (((size_t)(z + 1) * PD + (y + 1)) * PD
                                  + (x0 + n16 + 1)) * 32 + g * 8;
                *(uint2*)yb = pk.v;
            }
        }
    }
}

// ---------------------------------------------------------------------------
extern "C" void kernel_launch(void* const* d_in, const int* in_sizes, int n_in,
                              void* d_out, int out_size, void* d_ws, size_t ws_size,
                              hipStream_t stream)
{
    (void)in_sizes; (void)n_in; (void)out_size; (void)ws_size;
    const float* x     = (const float*)d_in[0];
    // d_in[1] = integration_time (unused; dt=0.05, 20 steps fixed)
    const float* w1    = (const float*)d_in[2];
    const float* b1    = (const float*)d_in[3];
    const float* w2    = (const float*)d_in[4];
    const float* b2    = (const float*)d_in[5];
    const float* noise = (const float*)d_in[6];

    char* ws = (char*)d_ws;
    unsigned short* w1t = (unsigned short*)ws;           // 55296 B
    unsigned short* w2t = (unsigned short*)(ws + 55296); // 55296 B
    char* ybp = ws + 131072;                             // 66^3*32  = 9,199,872 B
    char* hbp = ws + 131072 + 9199872;                   // 66^3*128 = 36,799,488 B
    float* y  = (float*)d_out;

    // zero both padded volumes (pads must be 0; interior rewritten each step)
    zero_ws<<<2048, 256, 0, stream>>>((uint4*)ybp, (9199872u + 36799488u) / 16u);
    prep_weights<<<108, 256, 0, stream>>>(w1, w2, w1t, w2t);
    pack_x<<<1024, 256, 0, stream>>>(x, ybp);

    for (int s = 0; s < 20; ++s) {
        conv1_mfma<<<dim3(8, 64), 256, 0, stream>>>(
            ybp, (const uint4*)w1t, b1, hbp);
        const float* ys = (s == 0) ? x : (const float*)y;
        conv2_mfma<<<dim3(4, 64, 8), 128, 0, stream>>>(
            hbp, (const uint4*)w2t, b2, ys, y, ybp,
            noise + (size_t)s * (16 * SSS));
    }
}